// Round 11
// baseline (230.470 us; speedup 1.0000x reference)
//
#include <hip/hip_runtime.h>
#include <cstdint>
#include <cstddef>

typedef __attribute__((ext_vector_type(8))) short bf16x8;
typedef __attribute__((ext_vector_type(4))) float f32x4;
typedef __attribute__((ext_vector_type(16))) float f32x16;

constexpr int Bsz = 4, Ssz = 2048, Dsz = 1024, Hn = 16, HDsz = 64;
constexpr int Msz = Bsz * Ssz; // 8192 rows of x
constexpr float LOG2E = 1.4426950408889634f;

// NOTE: do NOT gate amdgcn builtins with __has_builtin — it returns false
// in the HIP host pass.
#define MFMA32(a, b, c) __builtin_amdgcn_mfma_f32_16x16x32_bf16(a, b, c, 0, 0, 0)
#define MFMA3232(a, b, c) __builtin_amdgcn_mfma_f32_32x32x16_bf16(a, b, c, 0, 0, 0)

__device__ __forceinline__ unsigned short f2bf(float f) {
  union { float f; unsigned int u; } v; v.f = f;
  unsigned int r = v.u + 0x7fffu + ((v.u >> 16) & 1u);
  return (unsigned short)(r >> 16);
}

// v_cvt_pk_bf16_f32: dst = {lo: bf16(a), hi: bf16(b)} (T12 recipe, no builtin)
__device__ __forceinline__ int cvtpk(float a, float b) {
  int r;
  asm("v_cvt_pk_bf16_f32 %0, %1, %2" : "=v"(r) : "v"(a), "v"(b));
  return r;
}
// v_permlane32_swap_b32: a.hi-lanes <-> b.lo-lanes.
__device__ __forceinline__ void pswap(int& a, int& b) {
  asm("v_permlane32_swap_b32 %0, %1" : "+v"(a), "+v"(b));
}

// async 16B global -> LDS (wave-uniform LDS base + lane*16)
typedef __attribute__((address_space(1))) const unsigned int gu32;
typedef __attribute__((address_space(3))) unsigned int lu32;
__device__ __forceinline__ void async_cp16(const unsigned short* g, unsigned short* l) {
  __builtin_amdgcn_global_load_lds((gu32*)g, (lu32*)l, 16, 0, 0);
}

// ---------- fused: 4x W-transpose (z=0..3) + x fp32->bf16 (z=4) ----------
__global__ void prep_kernel(const float* __restrict__ x, unsigned short* __restrict__ xb,
                            const float* __restrict__ W0, const float* __restrict__ W1,
                            const float* __restrict__ W2, const float* __restrict__ W3,
                            unsigned short* __restrict__ T0, unsigned short* __restrict__ T1,
                            unsigned short* __restrict__ T2, unsigned short* __restrict__ T3) {
  const int z = blockIdx.z;
  if (z == 4) {  // x convert: 1024 blocks x 256 thr x 8 float4
    const int i0 = (blockIdx.y * 32 + blockIdx.x) * 2048 + threadIdx.x;
#pragma unroll
    for (int j = 0; j < 8; j++) {
      const int i = i0 + j * 256;
      const float4 v = reinterpret_cast<const float4*>(x)[i];
      ushort4 o;
      o.x = f2bf(v.x); o.y = f2bf(v.y); o.z = f2bf(v.z); o.w = f2bf(v.w);
      reinterpret_cast<ushort4*>(xb)[i] = o;
    }
    return;
  }
  __shared__ float tile[32][33];
  const float* W = (z == 0) ? W0 : (z == 1) ? W1 : (z == 2) ? W2 : W3;
  unsigned short* Wt = (z == 0) ? T0 : (z == 1) ? T1 : (z == 2) ? T2 : T3;
  int tx = threadIdx.x & 31, ty = threadIdx.x >> 5; // 32 x 8
  int bx = blockIdx.x, by = blockIdx.y;
#pragma unroll
  for (int i = 0; i < 4; i++) {
    int k = by * 32 + ty + i * 8;
    tile[ty + i * 8][tx] = W[k * Dsz + bx * 32 + tx];
  }
  __syncthreads();
#pragma unroll
  for (int i = 0; i < 4; i++) {
    int nrow = bx * 32 + ty + i * 8;
    Wt[nrow * Dsz + by * 32 + tx] = f2bf(tile[tx][ty + i * 8]);
  }
}

// ---------- 128x128-tile QKV GEMM, BK=64, 512 threads (8 waves, 32x64 acc/wave) ----------
// XOR-swizzled async-staged bf16 GEMM, C = A[M,K] * Bt[N,K]^T.
// bm-chunked bijective XCD swizzle (verified r2: FETCH 103->41MB; r4 here:
// 76.8->49.2MB): XCD x owns bm in [8x,8x+8) x all bn -> per-XCD A = 2MB
// (L2-resident), B panel shared via L3.
__global__ __launch_bounds__(512, 4)
void gemm_qkv(const unsigned short* __restrict__ A,
              const unsigned short* __restrict__ Bt,
              unsigned short* __restrict__ Qh,
              unsigned short* __restrict__ Kh,
              unsigned short* __restrict__ Vth) {
  __shared__ unsigned short As[128 * 64];
  __shared__ unsigned short Bs[128 * 64];

  const int tid = threadIdx.x;
  const int w = tid >> 6, lane = tid & 63;
  const int l15 = lane & 15, quad = lane >> 4;
  const int wr = w >> 1, wc = w & 1;
  const int orig = blockIdx.y * gridDim.x + blockIdx.x;
  const int xcd = orig & 7, idx = orig >> 3;
  const int bm = (xcd << 3) | (idx & 7);
  const int bn = idx >> 3;
  const int rr = lane >> 3;                 // row within 8-row group
  const int scoff = ((lane & 7) ^ rr) * 8;  // swizzled source col (shorts)

  f32x4 acc[2][4];
#pragma unroll
  for (int i = 0; i < 2; i++)
#pragma unroll
    for (int j = 0; j < 4; j++) acc[i][j] = (f32x4){0.f, 0.f, 0.f, 0.f};

  const int rowA0 = bm * 128, rowB0 = bn * 128;

  for (int kt = 0; kt < Dsz / 64; kt++) {
#pragma unroll
    for (int i = 0; i < 2; i++) {
      const int r8 = w * 16 + i * 8;
      async_cp16(&A[(size_t)(rowA0 + r8 + rr) * Dsz + kt * 64 + scoff], &As[r8 * 64]);
      async_cp16(&Bt[(size_t)(rowB0 + r8 + rr) * Dsz + kt * 64 + scoff], &Bs[r8 * 64]);
    }
    __syncthreads();

#pragma unroll
    for (int ks = 0; ks < 2; ks++) {
      bf16x8 af[2], bfr[4];
#pragma unroll
      for (int t = 0; t < 2; t++) {
        const int ra = wr * 32 + t * 16 + l15;
        af[t] = *reinterpret_cast<const bf16x8*>(
            &As[ra * 64 + (((ks * 4 + quad) ^ (ra & 7)) * 8)]);
      }
#pragma unroll
      for (int t = 0; t < 4; t++) {
        const int rb = wc * 64 + t * 16 + l15;
        bfr[t] = *reinterpret_cast<const bf16x8*>(
            &Bs[rb * 64 + (((ks * 4 + quad) ^ (rb & 7)) * 8)]);
      }
#pragma unroll
      for (int i = 0; i < 2; i++)
#pragma unroll
        for (int j = 0; j < 4; j++)
          acc[i][j] = MFMA32(af[i], bfr[j], acc[i][j]);
    }
    __syncthreads();
  }

  const int proj = (bn * 128) >> 10;  // block-uniform: 0=Q 1=K 2=V
#pragma unroll
  for (int i = 0; i < 2; i++) {
#pragma unroll
    for (int j = 0; j < 4; j++) {
      const int n = bn * 128 + wc * 64 + j * 16 + l15;
      const int nn = n & 1023, h = nn >> 6, hd = nn & 63;
      const int m0 = bm * 128 + wr * 32 + i * 16 + quad * 4;
      const int b = m0 >> 11, s0 = m0 & (Ssz - 1);
      if (proj == 0) {
#pragma unroll
        for (int r = 0; r < 4; r++)
          Qh[((size_t)(b * Hn + h) * Ssz + s0 + r) * HDsz + hd] =
              f2bf(acc[i][j][r] * (0.125f * LOG2E));
      } else if (proj == 1) {
#pragma unroll
        for (int r = 0; r < 4; r++)
          Kh[((size_t)(b * Hn + h) * Ssz + s0 + r) * HDsz + hd] = f2bf(acc[i][j][r]);
      } else {
        ushort4 o;
        o.x = f2bf(acc[i][j][0]); o.y = f2bf(acc[i][j][1]);
        o.z = f2bf(acc[i][j][2]); o.w = f2bf(acc[i][j][3]);
        *reinterpret_cast<ushort4*>(
            &Vth[((size_t)(b * Hn + h) * HDsz + hd) * Ssz + s0]) = o;
      }
    }
  }
}

// ---------- OUT projection: 128x64 tiles -> 1024 blocks = 4/CU full round ----------
// ROUND-11 CHANGE: at 128x128 the OUT grid was 512 blocks = 2 blocks/CU; the
// cross-round latency model gives T_b(2/CU) ~ 61us vs T_b(4/CU) ~ 42us — the
// barrier drain that cross-block TLP hides (m114) was exposed. 128x64 tiles
// give 1024 blocks = exactly 4/CU in one round, per-block work halved.
// 8 waves as 4x2: per-wave 32x32 acc (2x2 frags). LDS 24KB (As 16K + Bs 8K).
// Same XOR swizzle; same bm-chunked bijective XCD swizzle (A = 2MB/XCD).
__global__ __launch_bounds__(512, 4)
void gemm_out64(const unsigned short* __restrict__ A,
                const unsigned short* __restrict__ Bt,
                float* __restrict__ Out,
                const float* __restrict__ bias) {
  __shared__ unsigned short As[128 * 64];
  __shared__ unsigned short Bs[64 * 64];

  const int tid = threadIdx.x;
  const int w = tid >> 6, lane = tid & 63;
  const int l15 = lane & 15, quad = lane >> 4;
  const int wr = w >> 1, wc = w & 1;  // 4 x 2 wave grid
  const int orig = blockIdx.y * gridDim.x + blockIdx.x;  // grid (16, 64)
  const int xcd = orig & 7, idx = orig >> 3;              // idx 0..127
  const int bm = (xcd << 3) | (idx & 7);                  // 0..63
  const int bn = idx >> 3;                                // 0..15
  const int rr = lane >> 3;
  const int scoff = ((lane & 7) ^ rr) * 8;

  f32x4 acc[2][2];
#pragma unroll
  for (int i = 0; i < 2; i++)
#pragma unroll
    for (int j = 0; j < 2; j++) acc[i][j] = (f32x4){0.f, 0.f, 0.f, 0.f};

  const int rowA0 = bm * 128, rowB0 = bn * 64;

  for (int kt = 0; kt < Dsz / 64; kt++) {
#pragma unroll
    for (int i = 0; i < 2; i++) {
      const int r8 = w * 16 + i * 8;
      async_cp16(&A[(size_t)(rowA0 + r8 + rr) * Dsz + kt * 64 + scoff], &As[r8 * 64]);
    }
    {
      const int r8 = w * 8;
      async_cp16(&Bt[(size_t)(rowB0 + r8 + rr) * Dsz + kt * 64 + scoff], &Bs[r8 * 64]);
    }
    __syncthreads();

#pragma unroll
    for (int ks = 0; ks < 2; ks++) {
      bf16x8 af[2], bfr[2];
#pragma unroll
      for (int t = 0; t < 2; t++) {
        const int ra = wr * 32 + t * 16 + l15;
        af[t] = *reinterpret_cast<const bf16x8*>(
            &As[ra * 64 + (((ks * 4 + quad) ^ (ra & 7)) * 8)]);
      }
#pragma unroll
      for (int t = 0; t < 2; t++) {
        const int rb = wc * 32 + t * 16 + l15;
        bfr[t] = *reinterpret_cast<const bf16x8*>(
            &Bs[rb * 64 + (((ks * 4 + quad) ^ (rb & 7)) * 8)]);
      }
#pragma unroll
      for (int i = 0; i < 2; i++)
#pragma unroll
        for (int j = 0; j < 2; j++)
          acc[i][j] = MFMA32(af[i], bfr[j], acc[i][j]);
    }
    __syncthreads();
  }

#pragma unroll
  for (int i = 0; i < 2; i++) {
#pragma unroll
    for (int j = 0; j < 2; j++) {
      const int n = bn * 64 + wc * 32 + j * 16 + l15;
      const int m0 = bm * 128 + wr * 32 + i * 16 + quad * 4;
#pragma unroll
      for (int r = 0; r < 4; r++)
        Out[(size_t)(m0 + r) * Dsz + n] = acc[i][j][r] + bias[n];
    }
  }
}

// ---------- flash attention v9: 32x32 MFMA + counted-drain double-buffer ----------
// (r10 accounting: v9 ~ -12us vs v8 after clock normalization — keep.)
// v7/v8 math byte-for-byte (swapped QK^T, in-reg softmax, cvt_pk +
// permlane32_swap, PV on 32x32x16, setprio around MFMA clusters).
// T3/T4 minimum 2-phase recipe: 64-kv tiles, TWO buffer pairs (32KB total,
// 4 blocks/CU), per iter: { __syncthreads (drains stage(kb) issued one FULL
// compute phase ago); stage(kb+1) into the other buffer; compute(kb) }.
__global__ __launch_bounds__(256, 4)
void flash_kernel(const unsigned short* __restrict__ Q,
                  const unsigned short* __restrict__ Kg,
                  const unsigned short* __restrict__ Vt,
                  unsigned short* __restrict__ AO) {
  __shared__ unsigned short Ks0[64 * 64];
  __shared__ unsigned short Vs0[64 * 64];
  __shared__ unsigned short Ks1[64 * 64];
  __shared__ unsigned short Vs1[64 * 64];

  const int tid = threadIdx.x;
  const int w = tid >> 6, lane = tid & 63;
  const int l31 = lane & 31, hi = lane >> 5;
  const int rr = lane >> 3;

  const int linear = blockIdx.y * 16 + blockIdx.x;
  const int bh = (linear & 7) * 8 + ((linear >> 3) & 7);
  const int g = linear >> 6, gk = g >> 2, ga = g & 3;
  const int t = (gk == 0) ? 15 - ga : (gk == 1) ? 8 + ga : (gk == 2) ? 7 - ga : ga;

  const unsigned short* Qb = Q + (size_t)bh * Ssz * HDsz;
  const unsigned short* Kb = Kg + (size_t)bh * Ssz * HDsz;
  const unsigned short* Vb = Vt + (size_t)bh * HDsz * Ssz;
  const int b = bh / Hn, h = bh % Hn;

  const int hl = (l31 & 7) ^ (((l31 >> 3) & 1) << 2);

  const int rowStart = t * 128 + w * 32;
  const int q = rowStart + l31;

  auto stage = [&](unsigned short* Kd, unsigned short* Vd, int kb2) {
    const int kv0s = kb2 * 64;
#pragma unroll
    for (int i = 0; i < 2; i++) {
      const int r8 = w * 16 + i * 8;
      const int sc = (((lane & 7) ^ rr ^ (i << 2))) * 8;
      async_cp16(&Kb[(size_t)(kv0s + r8 + rr) * HDsz + sc], &Kd[r8 * 64]);
      async_cp16(&Vb[(size_t)(r8 + rr) * Ssz + kv0s + sc], &Vd[r8 * 64]);
    }
  };

  bf16x8 qf[4];
#pragma unroll
  for (int ks = 0; ks < 4; ks++)
    qf[ks] = *reinterpret_cast<const bf16x8*>(
        &Qb[(size_t)q * HDsz + ks * 16 + hi * 8]);

  f32x16 oacc[2];
#pragma unroll
  for (int ho = 0; ho < 2; ho++)
#pragma unroll
    for (int r = 0; r < 16; r++) oacc[ho][r] = 0.f;
  float lpart = 0.f;

  const int nkb = 2 * t + 2;
  stage(Ks0, Vs0, 0);
  for (int kb = 0; kb < nkb; kb++) {
    __syncthreads();
    const unsigned short* Ksc = (kb & 1) ? Ks1 : Ks0;
    const unsigned short* Vsc = (kb & 1) ? Vs1 : Vs0;
    if (kb + 1 < nkb) {
      if (kb & 1) stage(Ks0, Vs0, kb + 1);
      else        stage(Ks1, Vs1, kb + 1);
    }

    const int kv0 = kb * 64;
#pragma unroll
    for (int kt = 0; kt < 2; kt++) {
      const bool skip = (kv0 + kt * 32 >= rowStart + 32);  // wave-uniform
      if (skip) continue;

      f32x16 st;
#pragma unroll
      for (int r = 0; r < 16; r++) st[r] = 0.f;
      __builtin_amdgcn_s_setprio(1);
#pragma unroll
      for (int ks = 0; ks < 4; ks++) {
        const int row = kt * 32 + l31;
        bf16x8 kf = *reinterpret_cast<const bf16x8*>(
            &Ksc[row * 64 + (((ks * 2 + hi) ^ hl) * 8)]);
        st = MFMA3232(kf, qf[ks], st);
      }
      __builtin_amdgcn_s_setprio(0);

      const bool needMask = (kv0 + kt * 32 + 31 > rowStart);  // wave-uniform
      if (needMask) {
#pragma unroll
        for (int r = 0; r < 16; r++) {
          const int kv = kv0 + kt * 32 + (r & 3) + 8 * (r >> 2) + 4 * hi;
          if (kv > q) st[r] = -1e30f;
        }
      }

      float e[16];
#pragma unroll
      for (int r = 0; r < 16; r++) e[r] = __builtin_amdgcn_exp2f(st[r]);
#pragma unroll
      for (int r = 0; r < 16; r += 4)
        lpart += (e[r] + e[r + 1]) + (e[r + 2] + e[r + 3]);

#pragma unroll
      for (int s = 0; s < 2; s++) {
        int a0 = cvtpk(e[8 * s + 0], e[8 * s + 1]);
        int a1 = cvtpk(e[8 * s + 2], e[8 * s + 3]);
        int b0 = cvtpk(e[8 * s + 4], e[8 * s + 5]);
        int b1 = cvtpk(e[8 * s + 6], e[8 * s + 7]);
        pswap(a0, b0);  // -> words 0, 2
        pswap(a1, b1);  // -> words 1, 3
        union { int u[4]; bf16x8 v; } pa;
        pa.u[0] = a0; pa.u[1] = a1; pa.u[2] = b0; pa.u[3] = b1;
        const int t16 = kt * 2 + s;
        __builtin_amdgcn_s_setprio(1);
#pragma unroll
        for (int ho = 0; ho < 2; ho++) {
          const int row = ho * 32 + l31;
          bf16x8 vf = *reinterpret_cast<const bf16x8*>(
              &Vsc[row * 64 + (((t16 * 2 + hi) ^ hl) * 8)]);
          oacc[ho] = MFMA3232(pa.v, vf, oacc[ho]);
        }
        __builtin_amdgcn_s_setprio(0);
      }
    }
  }

  float lf = lpart + __shfl_xor(lpart, 32);
  float linv[16];
#pragma unroll
  for (int r = 0; r < 16; r++) {
    const int qloc = (r & 3) + 8 * (r >> 2) + 4 * hi;
    union { float f; int i; } cv;
    cv.f = lf;
    cv.i = __builtin_amdgcn_ds_bpermute(qloc * 4, cv.i);
    linv[r] = 1.f / cv.f;
  }
#pragma unroll
  for (int r = 0; r < 16; r++) {
    const int qloc = (r & 3) + 8 * (r >> 2) + 4 * hi;
    const size_t m = (size_t)b * Ssz + rowStart + qloc;
#pragma unroll
    for (int ho = 0; ho < 2; ho++) {
      const int n = h * HDsz + ho * 32 + l31;
      AO[m * Dsz + n] = f2bf(oacc[ho][r] * linv[r]);
    }
  }
}

extern "C" void kernel_launch(void* const* d_in, const int* in_sizes, int n_in,
                              void* d_out, int out_size, void* d_ws, size_t ws_size,
                              hipStream_t stream) {
  const float* x  = (const float*)d_in[0];
  const float* Wq = (const float*)d_in[1];
  const float* Wk = (const float*)d_in[2];
  const float* Wv = (const float*)d_in[3];
  const float* Wo = (const float*)d_in[4];
  const float* bo = (const float*)d_in[5];
  float* out = (float*)d_out;

  unsigned short* xb  = (unsigned short*)d_ws;
  unsigned short* Wqt = xb + (size_t)Msz * Dsz;   // Wqt/Wkt/Wvt consecutive = concat [3072][1024]
  unsigned short* Wkt = Wqt + (size_t)Dsz * Dsz;
  unsigned short* Wvt = Wkt + (size_t)Dsz * Dsz;
  unsigned short* Wot = Wvt + (size_t)Dsz * Dsz;
  unsigned short* Qh  = Wot + (size_t)Dsz * Dsz;
  unsigned short* Kh  = Qh + (size_t)Msz * Dsz;
  unsigned short* Vth = Kh + (size_t)Msz * Dsz;
  unsigned short* AO  = Vth + (size_t)Msz * Dsz;

  prep_kernel<<<dim3(32, 32, 5), 256, 0, stream>>>(
      x, xb, Wq, Wk, Wv, Wo, Wqt, Wkt, Wvt, Wot);

  // fused QKV projection: N = 3072 (proven 128x128 structure + XCD swizzle)
  gemm_qkv<<<dim3(3 * Dsz / 128, Msz / 128), 512, 0, stream>>>(
      xb, Wqt, Qh, Kh, Vth);

  flash_kernel<<<dim3(16, Bsz * Hn), 256, 0, stream>>>(Qh, Kh, Vth, AO);

  // OUT projection: 128x64 tiles -> 1024 blocks = 4/CU (was 512 = 2/CU)
  gemm_out64<<<dim3(Dsz / 64, Msz / 128), 512, 0, stream>>>(AO, Wot, out, bo);
}

// Round 12
// 222.466 us; speedup vs baseline: 1.0360x; 1.0360x over previous
//
#include <hip/hip_runtime.h>
#include <cstdint>
#include <cstddef>

typedef __attribute__((ext_vector_type(8))) short bf16x8;
typedef __attribute__((ext_vector_type(4))) float f32x4;
typedef __attribute__((ext_vector_type(16))) float f32x16;

constexpr int Bsz = 4, Ssz = 2048, Dsz = 1024, Hn = 16, HDsz = 64;
constexpr int Msz = Bsz * Ssz; // 8192 rows of x
constexpr float LOG2E = 1.4426950408889634f;

// NOTE: do NOT gate amdgcn builtins with __has_builtin — it returns false
// in the HIP host pass.
#define MFMA32(a, b, c) __builtin_amdgcn_mfma_f32_16x16x32_bf16(a, b, c, 0, 0, 0)
#define MFMA3232(a, b, c) __builtin_amdgcn_mfma_f32_32x32x16_bf16(a, b, c, 0, 0, 0)

__device__ __forceinline__ unsigned short f2bf(float f) {
  union { float f; unsigned int u; } v; v.f = f;
  unsigned int r = v.u + 0x7fffu + ((v.u >> 16) & 1u);
  return (unsigned short)(r >> 16);
}

// v_cvt_pk_bf16_f32: dst = {lo: bf16(a), hi: bf16(b)} (T12 recipe, no builtin)
__device__ __forceinline__ int cvtpk(float a, float b) {
  int r;
  asm("v_cvt_pk_bf16_f32 %0, %1, %2" : "=v"(r) : "v"(a), "v"(b));
  return r;
}
// v_permlane32_swap_b32: a.hi-lanes <-> b.lo-lanes.
__device__ __forceinline__ void pswap(int& a, int& b) {
  asm("v_permlane32_swap_b32 %0, %1" : "+v"(a), "+v"(b));
}

// async 16B global -> LDS (wave-uniform LDS base + lane*16)
typedef __attribute__((address_space(1))) const unsigned int gu32;
typedef __attribute__((address_space(3))) unsigned int lu32;
__device__ __forceinline__ void async_cp16(const unsigned short* g, unsigned short* l) {
  __builtin_amdgcn_global_load_lds((gu32*)g, (lu32*)l, 16, 0, 0);
}

// ---------- fused: 4x W-transpose (z=0..3) + x fp32->bf16 (z=4) ----------
__global__ void prep_kernel(const float* __restrict__ x, unsigned short* __restrict__ xb,
                            const float* __restrict__ W0, const float* __restrict__ W1,
                            const float* __restrict__ W2, const float* __restrict__ W3,
                            unsigned short* __restrict__ T0, unsigned short* __restrict__ T1,
                            unsigned short* __restrict__ T2, unsigned short* __restrict__ T3) {
  const int z = blockIdx.z;
  if (z == 4) {  // x convert: 1024 blocks x 256 thr x 8 float4
    const int i0 = (blockIdx.y * 32 + blockIdx.x) * 2048 + threadIdx.x;
#pragma unroll
    for (int j = 0; j < 8; j++) {
      const int i = i0 + j * 256;
      const float4 v = reinterpret_cast<const float4*>(x)[i];
      ushort4 o;
      o.x = f2bf(v.x); o.y = f2bf(v.y); o.z = f2bf(v.z); o.w = f2bf(v.w);
      reinterpret_cast<ushort4*>(xb)[i] = o;
    }
    return;
  }
  __shared__ float tile[32][33];
  const float* W = (z == 0) ? W0 : (z == 1) ? W1 : (z == 2) ? W2 : W3;
  unsigned short* Wt = (z == 0) ? T0 : (z == 1) ? T1 : (z == 2) ? T2 : T3;
  int tx = threadIdx.x & 31, ty = threadIdx.x >> 5; // 32 x 8
  int bx = blockIdx.x, by = blockIdx.y;
#pragma unroll
  for (int i = 0; i < 4; i++) {
    int k = by * 32 + ty + i * 8;
    tile[ty + i * 8][tx] = W[k * Dsz + bx * 32 + tx];
  }
  __syncthreads();
#pragma unroll
  for (int i = 0; i < 4; i++) {
    int nrow = bx * 32 + ty + i * 8;
    Wt[nrow * Dsz + by * 32 + tx] = f2bf(tile[tx][ty + i * 8]);
  }
}

// ---------- 128x128-tile, BK=64, 512 threads (8 waves, 32x64 acc/wave) ----------
// XOR-swizzled async-staged bf16 GEMM, C = A[M,K] * Bt[N,K]^T.
// bm-chunked bijective XCD swizzle (verified r2: FETCH 103->41MB; r4 here:
// 76.8->49.2MB): XCD x owns bm in [8x,8x+8) x all bn -> per-XCD A = 2MB
// (L2-resident), B panel shared via L3.
// r11 lesson: 128x64 OUT tiles (2x blocks, same barriers/block) REGRESSED
// ~+7us — barrier-drain events scale with block count; 128x128 @ 2 blocks/CU
// is the better point for OUT. Do not shrink tiles here.
enum { EPI_QKV = 0, EPI_OUT = 1 };

template <int EPI>
__global__ __launch_bounds__(512, 4)
void gemm_bk64(const unsigned short* __restrict__ A,
               const unsigned short* __restrict__ Bt,
               unsigned short* __restrict__ Qh,
               unsigned short* __restrict__ Kh,
               unsigned short* __restrict__ Vth,
               float* __restrict__ Out,
               const float* __restrict__ bias) {
  __shared__ unsigned short As[128 * 64];
  __shared__ unsigned short Bs[128 * 64];

  const int tid = threadIdx.x;
  const int w = tid >> 6, lane = tid & 63;
  const int l15 = lane & 15, quad = lane >> 4;
  const int wr = w >> 1, wc = w & 1;
  const int orig = blockIdx.y * gridDim.x + blockIdx.x;
  const int xcd = orig & 7, idx = orig >> 3;
  const int bm = (xcd << 3) | (idx & 7);
  const int bn = idx >> 3;
  const int rr = lane >> 3;                 // row within 8-row group
  const int scoff = ((lane & 7) ^ rr) * 8;  // swizzled source col (shorts)

  f32x4 acc[2][4];
#pragma unroll
  for (int i = 0; i < 2; i++)
#pragma unroll
    for (int j = 0; j < 4; j++) acc[i][j] = (f32x4){0.f, 0.f, 0.f, 0.f};

  const int rowA0 = bm * 128, rowB0 = bn * 128;

  for (int kt = 0; kt < Dsz / 64; kt++) {
#pragma unroll
    for (int i = 0; i < 2; i++) {
      const int r8 = w * 16 + i * 8;
      async_cp16(&A[(size_t)(rowA0 + r8 + rr) * Dsz + kt * 64 + scoff], &As[r8 * 64]);
      async_cp16(&Bt[(size_t)(rowB0 + r8 + rr) * Dsz + kt * 64 + scoff], &Bs[r8 * 64]);
    }
    __syncthreads();

#pragma unroll
    for (int ks = 0; ks < 2; ks++) {
      bf16x8 af[2], bfr[4];
#pragma unroll
      for (int t = 0; t < 2; t++) {
        const int ra = wr * 32 + t * 16 + l15;
        af[t] = *reinterpret_cast<const bf16x8*>(
            &As[ra * 64 + (((ks * 4 + quad) ^ (ra & 7)) * 8)]);
      }
#pragma unroll
      for (int t = 0; t < 4; t++) {
        const int rb = wc * 64 + t * 16 + l15;
        bfr[t] = *reinterpret_cast<const bf16x8*>(
            &Bs[rb * 64 + (((ks * 4 + quad) ^ (rb & 7)) * 8)]);
      }
#pragma unroll
      for (int i = 0; i < 2; i++)
#pragma unroll
        for (int j = 0; j < 4; j++)
          acc[i][j] = MFMA32(af[i], bfr[j], acc[i][j]);
    }
    __syncthreads();
  }

  if (EPI == EPI_QKV) {
    const int proj = (bn * 128) >> 10;  // block-uniform: 0=Q 1=K 2=V
#pragma unroll
    for (int i = 0; i < 2; i++) {
#pragma unroll
      for (int j = 0; j < 4; j++) {
        const int n = bn * 128 + wc * 64 + j * 16 + l15;
        const int nn = n & 1023, h = nn >> 6, hd = nn & 63;
        const int m0 = bm * 128 + wr * 32 + i * 16 + quad * 4;
        const int b = m0 >> 11, s0 = m0 & (Ssz - 1);
        if (proj == 0) {
#pragma unroll
          for (int r = 0; r < 4; r++)
            Qh[((size_t)(b * Hn + h) * Ssz + s0 + r) * HDsz + hd] =
                f2bf(acc[i][j][r] * (0.125f * LOG2E));
        } else if (proj == 1) {
#pragma unroll
          for (int r = 0; r < 4; r++)
            Kh[((size_t)(b * Hn + h) * Ssz + s0 + r) * HDsz + hd] = f2bf(acc[i][j][r]);
        } else {
          ushort4 o;
          o.x = f2bf(acc[i][j][0]); o.y = f2bf(acc[i][j][1]);
          o.z = f2bf(acc[i][j][2]); o.w = f2bf(acc[i][j][3]);
          *reinterpret_cast<ushort4*>(
              &Vth[((size_t)(b * Hn + h) * HDsz + hd) * Ssz + s0]) = o;
        }
      }
    }
  } else {
#pragma unroll
    for (int i = 0; i < 2; i++) {
#pragma unroll
      for (int j = 0; j < 4; j++) {
        const int n = bn * 128 + wc * 64 + j * 16 + l15;
        const int m0 = bm * 128 + wr * 32 + i * 16 + quad * 4;
#pragma unroll
        for (int r = 0; r < 4; r++)
          Out[(size_t)(m0 + r) * Dsz + n] = acc[i][j][r] + bias[n];
      }
    }
  }
}

// ---------- flash attention v9: 32x32 MFMA + counted-drain double-buffer ----------
// v7/v8 math byte-for-byte (swapped QK^T, in-reg softmax, cvt_pk +
// permlane32_swap, PV on 32x32x16, setprio around MFMA clusters).
// T3/T4 minimum 2-phase recipe: 64-kv tiles, TWO buffer pairs (32KB total,
// 4 blocks/CU), per iter: { __syncthreads (drains stage(kb) issued one FULL
// compute phase ago -> near-instant); stage(kb+1) into other buffer;
// compute(kb) }. Race-safe: buffer being staged was last read in kb-1,
// behind a barrier.
__global__ __launch_bounds__(256, 4)
void flash_kernel(const unsigned short* __restrict__ Q,
                  const unsigned short* __restrict__ Kg,
                  const unsigned short* __restrict__ Vt,
                  unsigned short* __restrict__ AO) {
  __shared__ unsigned short Ks0[64 * 64];
  __shared__ unsigned short Vs0[64 * 64];
  __shared__ unsigned short Ks1[64 * 64];
  __shared__ unsigned short Vs1[64 * 64];

  const int tid = threadIdx.x;
  const int w = tid >> 6, lane = tid & 63;
  const int l31 = lane & 31, hi = lane >> 5;
  const int rr = lane >> 3;

  const int linear = blockIdx.y * 16 + blockIdx.x;
  const int bh = (linear & 7) * 8 + ((linear >> 3) & 7);
  const int g = linear >> 6, gk = g >> 2, ga = g & 3;
  const int t = (gk == 0) ? 15 - ga : (gk == 1) ? 8 + ga : (gk == 2) ? 7 - ga : ga;

  const unsigned short* Qb = Q + (size_t)bh * Ssz * HDsz;
  const unsigned short* Kb = Kg + (size_t)bh * Ssz * HDsz;
  const unsigned short* Vb = Vt + (size_t)bh * HDsz * Ssz;
  const int b = bh / Hn, h = bh % Hn;

  const int hl = (l31 & 7) ^ (((l31 >> 3) & 1) << 2);

  const int rowStart = t * 128 + w * 32;
  const int q = rowStart + l31;

  auto stage = [&](unsigned short* Kd, unsigned short* Vd, int kb2) {
    const int kv0s = kb2 * 64;
#pragma unroll
    for (int i = 0; i < 2; i++) {
      const int r8 = w * 16 + i * 8;
      const int sc = (((lane & 7) ^ rr ^ (i << 2))) * 8;
      async_cp16(&Kb[(size_t)(kv0s + r8 + rr) * HDsz + sc], &Kd[r8 * 64]);
      async_cp16(&Vb[(size_t)(r8 + rr) * Ssz + kv0s + sc], &Vd[r8 * 64]);
    }
  };

  bf16x8 qf[4];
#pragma unroll
  for (int ks = 0; ks < 4; ks++)
    qf[ks] = *reinterpret_cast<const bf16x8*>(
        &Qb[(size_t)q * HDsz + ks * 16 + hi * 8]);

  f32x16 oacc[2];
#pragma unroll
  for (int ho = 0; ho < 2; ho++)
#pragma unroll
    for (int r = 0; r < 16; r++) oacc[ho][r] = 0.f;
  float lpart = 0.f;

  const int nkb = 2 * t + 2;
  stage(Ks0, Vs0, 0);
  for (int kb = 0; kb < nkb; kb++) {
    __syncthreads();
    const unsigned short* Ksc = (kb & 1) ? Ks1 : Ks0;
    const unsigned short* Vsc = (kb & 1) ? Vs1 : Vs0;
    if (kb + 1 < nkb) {
      if (kb & 1) stage(Ks0, Vs0, kb + 1);
      else        stage(Ks1, Vs1, kb + 1);
    }

    const int kv0 = kb * 64;
#pragma unroll
    for (int kt = 0; kt < 2; kt++) {
      const bool skip = (kv0 + kt * 32 >= rowStart + 32);  // wave-uniform
      if (skip) continue;

      f32x16 st;
#pragma unroll
      for (int r = 0; r < 16; r++) st[r] = 0.f;
      __builtin_amdgcn_s_setprio(1);
#pragma unroll
      for (int ks = 0; ks < 4; ks++) {
        const int row = kt * 32 + l31;
        bf16x8 kf = *reinterpret_cast<const bf16x8*>(
            &Ksc[row * 64 + (((ks * 2 + hi) ^ hl) * 8)]);
        st = MFMA3232(kf, qf[ks], st);
      }
      __builtin_amdgcn_s_setprio(0);

      const bool needMask = (kv0 + kt * 32 + 31 > rowStart);  // wave-uniform
      if (needMask) {
#pragma unroll
        for (int r = 0; r < 16; r++) {
          const int kv = kv0 + kt * 32 + (r & 3) + 8 * (r >> 2) + 4 * hi;
          if (kv > q) st[r] = -1e30f;
        }
      }

      float e[16];
#pragma unroll
      for (int r = 0; r < 16; r++) e[r] = __builtin_amdgcn_exp2f(st[r]);
#pragma unroll
      for (int r = 0; r < 16; r += 4)
        lpart += (e[r] + e[r + 1]) + (e[r + 2] + e[r + 3]);

#pragma unroll
      for (int s = 0; s < 2; s++) {
        int a0 = cvtpk(e[8 * s + 0], e[8 * s + 1]);
        int a1 = cvtpk(e[8 * s + 2], e[8 * s + 3]);
        int b0 = cvtpk(e[8 * s + 4], e[8 * s + 5]);
        int b1 = cvtpk(e[8 * s + 6], e[8 * s + 7]);
        pswap(a0, b0);  // -> words 0, 2
        pswap(a1, b1);  // -> words 1, 3
        union { int u[4]; bf16x8 v; } pa;
        pa.u[0] = a0; pa.u[1] = a1; pa.u[2] = b0; pa.u[3] = b1;
        const int t16 = kt * 2 + s;
        __builtin_amdgcn_s_setprio(1);
#pragma unroll
        for (int ho = 0; ho < 2; ho++) {
          const int row = ho * 32 + l31;
          bf16x8 vf = *reinterpret_cast<const bf16x8*>(
              &Vsc[row * 64 + (((t16 * 2 + hi) ^ hl) * 8)]);
          oacc[ho] = MFMA3232(pa.v, vf, oacc[ho]);
        }
        __builtin_amdgcn_s_setprio(0);
      }
    }
  }

  float lf = lpart + __shfl_xor(lpart, 32);
  float linv[16];
#pragma unroll
  for (int r = 0; r < 16; r++) {
    const int qloc = (r & 3) + 8 * (r >> 2) + 4 * hi;
    union { float f; int i; } cv;
    cv.f = lf;
    cv.i = __builtin_amdgcn_ds_bpermute(qloc * 4, cv.i);
    linv[r] = 1.f / cv.f;
  }
#pragma unroll
  for (int r = 0; r < 16; r++) {
    const int qloc = (r & 3) + 8 * (r >> 2) + 4 * hi;
    const size_t m = (size_t)b * Ssz + rowStart + qloc;
#pragma unroll
    for (int ho = 0; ho < 2; ho++) {
      const int n = h * HDsz + ho * 32 + l31;
      AO[m * Dsz + n] = f2bf(oacc[ho][r] * linv[r]);
    }
  }
}

extern "C" void kernel_launch(void* const* d_in, const int* in_sizes, int n_in,
                              void* d_out, int out_size, void* d_ws, size_t ws_size,
                              hipStream_t stream) {
  const float* x  = (const float*)d_in[0];
  const float* Wq = (const float*)d_in[1];
  const float* Wk = (const float*)d_in[2];
  const float* Wv = (const float*)d_in[3];
  const float* Wo = (const float*)d_in[4];
  const float* bo = (const float*)d_in[5];
  float* out = (float*)d_out;

  unsigned short* xb  = (unsigned short*)d_ws;
  unsigned short* Wqt = xb + (size_t)Msz * Dsz;   // Wqt/Wkt/Wvt consecutive = concat [3072][1024]
  unsigned short* Wkt = Wqt + (size_t)Dsz * Dsz;
  unsigned short* Wvt = Wkt + (size_t)Dsz * Dsz;
  unsigned short* Wot = Wvt + (size_t)Dsz * Dsz;
  unsigned short* Qh  = Wot + (size_t)Dsz * Dsz;
  unsigned short* Kh  = Qh + (size_t)Msz * Dsz;
  unsigned short* Vth = Kh + (size_t)Msz * Dsz;
  unsigned short* AO  = Vth + (size_t)Msz * Dsz;

  prep_kernel<<<dim3(32, 32, 5), 256, 0, stream>>>(
      x, xb, Wq, Wk, Wv, Wo, Wqt, Wkt, Wvt, Wot);

  // fused QKV projection: N = 3072 (proven 128x128 structure + XCD swizzle)
  gemm_bk64<EPI_QKV><<<dim3(3 * Dsz / 128, Msz / 128), 512, 0, stream>>>(
      xb, Wqt, Qh, Kh, Vth, nullptr, nullptr);

  flash_kernel<<<dim3(16, Bsz * Hn), 256, 0, stream>>>(Qh, Kh, Vth, AO);

  gemm_bk64<EPI_OUT><<<dim3(Dsz / 128, Msz / 128), 512, 0, stream>>>(
      AO, Wot, nullptr, nullptr, nullptr, out, bo);
}